// Round 1
// baseline (512.765 us; speedup 1.0000x reference)
//
#include <hip/hip_runtime.h>
#include <math.h>

#define K_POLY   20000
#define PMAX     30
#define NUM_PTS  5
#define C_MID    112
#define C_OUT    224
#define PE_DIM   32
#define GEO_DIM  256
#define NUM_FREQS 8
#define POLYS    8
#define THREADS  256

__global__ __launch_bounds__(THREADS, 4) void geo_encoder(
    const float* __restrict__ geoms, const int* __restrict__ lengths,
    const float* __restrict__ w1, const float* __restrict__ b1,
    const float* __restrict__ w2, const float* __restrict__ b2,
    const float* __restrict__ gamma, const float* __restrict__ beta,
    const int* __restrict__ roi_w, const int* __restrict__ roi_h,
    float* __restrict__ out)
{
    __shared__ float s_geo[POLYS][PMAX][2];     // staged input coords
    __shared__ float s_cum[POLYS][PMAX];        // arclength cumsum
    __shared__ float s_seg[POLYS][PMAX - 1];    // segment lengths
    __shared__ float s_pts[POLYS][NUM_PTS][2];  // normalized resampled coords
    __shared__ float s_y1[POLYS][C_MID][8];     // conv1 out with halo: [0]=0,[1..5]=p0..4,[6,7]=0
    __shared__ float s_red[4][POLYS][NUM_PTS][2]; // per-wave partial (sum, sumsq)
    __shared__ float s_stats[POLYS][NUM_PTS][2];  // (mu, rstd)
    __shared__ int   s_len[POLYS];

    const int t  = threadIdx.x;
    const int k0 = blockIdx.x * POLYS;

    // ---- stage geoms (coalesced) + lengths ----
    {
        const float* src = geoms + (size_t)k0 * (PMAX * 2);
        float* dst = &s_geo[0][0][0];
        for (int i = t; i < POLYS * PMAX * 2; i += THREADS) dst[i] = src[i];
        if (t < POLYS) s_len[t] = lengths[k0 + t];
    }
    __syncthreads();

    // ---- zero halo slots of s_y1 (slots 0,6,7) ----
    for (int i = t; i < POLYS * C_MID * 3; i += THREADS) {
        int poly = i / (C_MID * 3);
        int r = i % (C_MID * 3);
        int c = r / 3, s = r % 3;
        int slot = (s == 0) ? 0 : 5 + s;
        s_y1[poly][c][slot] = 0.f;
    }

    // ---- phase A1: per-polyline seg/cum (matches jnp.cumsum order bitwise) ----
    if (t < POLYS) {
        int L = s_len[t];
        float cum = 0.f;
        s_cum[t][0] = 0.f;
        for (int i = 0; i < PMAX - 1; ++i) {
            float seg = 0.f;
            if (i < L - 1) {
                float dx = s_geo[t][i + 1][0] - s_geo[t][i][0];
                float dy = s_geo[t][i + 1][1] - s_geo[t][i][1];
                float sq = dx * dx + dy * dy;
                seg = (sq > 0.f) ? sqrtf(sq) : 0.f;
            }
            s_seg[t][i] = seg;
            cum += seg;
            s_cum[t][i + 1] = cum;
        }
    }
    __syncthreads();

    // ---- phase A2: resample one point per thread (40 threads) ----
    const float roiw  = (float)roi_w[0], roih = (float)roi_h[0];
    const float halfx = roiw * 0.5f, halfy = roih * 0.5f;
    if (t < POLYS * NUM_PTS) {
        int poly = t / NUM_PTS, j = t % NUM_PTS;
        int L = s_len[poly];
        float total = s_cum[poly][PMAX - 1];
        float px, py;
        if (total < 1e-6f) {
            px = s_geo[poly][0][0];
            py = s_geo[poly][0][1];
        } else {
            float target = total * (0.25f * (float)j);
            // searchsorted(cum, target, 'left'): smallest i with cum[i] >= target
            int idx = PMAX; // "not found" => len(cum)
            for (int i = 0; i < PMAX; ++i) {
                if (s_cum[poly][i] >= target) { idx = i; break; }
            }
            idx = max(1, min(idx, L - 1));
            float tt = (target - s_cum[poly][idx - 1]) / (s_seg[poly][idx - 1] + 1e-8f);
            float x0 = s_geo[poly][idx - 1][0], y0 = s_geo[poly][idx - 1][1];
            float dx = s_geo[poly][idx][0] - x0, dy = s_geo[poly][idx][1] - y0;
            px = x0 + tt * dx;
            py = y0 + tt * dy;
        }
        float cx = (px + halfx) / roiw;
        float cy = (py + halfy) / roih;
        s_pts[poly][j][0] = cx;
        s_pts[poly][j][1] = cy;
        size_t kk = (size_t)(k0 + poly);
        float* co = out + (size_t)K_POLY * NUM_PTS * GEO_DIM + (kk * NUM_PTS + j) * 2;
        co[0] = cx;
        co[1] = cy;
    }
    __syncthreads();

    // ---- PE: sinusoidal positional encoding, written straight to global ----
    for (int i = t; i < POLYS * NUM_PTS * PE_DIM; i += THREADS) {
        int poly = i / (NUM_PTS * PE_DIM);
        int r = i % (NUM_PTS * PE_DIM);
        int p = r / PE_DIM;
        int f = r % PE_DIM;
        int d = f >> 4;          // coord dim
        int inner = f & 15;
        int fr = inner & 7;      // frequency index
        int isc = inner >> 3;    // 0=sin, 1=cos
        float x = s_pts[poly][p][d];
        float arg = x * ((float)(1 << fr) * 3.14159265358979323846f);
        float v = isc ? cosf(arg) : sinf(arg);
        size_t kk = (size_t)(k0 + poly);
        out[(kk * NUM_PTS + p) * GEO_DIM + f] = v;
    }

    // ---- conv1 (2->112, k=3, pad 1) + ReLU into LDS halo layout ----
    for (int i = t; i < POLYS * NUM_PTS * C_MID; i += THREADS) {
        int c = i % C_MID;
        int r = i / C_MID;
        int p = r % NUM_PTS;
        int poly = r / NUM_PTS;
        float acc = b1[c];
        const float* w = w1 + c * 6;
        #pragma unroll
        for (int ch = 0; ch < 2; ++ch) {
            #pragma unroll
            for (int dk = 0; dk < 3; ++dk) {
                int pp = p + dk - 1;
                float xv = (pp >= 0 && pp < NUM_PTS) ? s_pts[poly][pp][ch] : 0.f;
                acc += xv * w[ch * 3 + dk];
            }
        }
        s_y1[poly][c][1 + p] = fmaxf(acc, 0.f);
    }
    __syncthreads();

    // ---- conv2 (112->224, k=3, pad 1) + ReLU, thread = out channel ----
    const int o = t;
    const bool valid = (o < C_OUT);
    float acc[POLYS][NUM_PTS];
    {
        float bias = valid ? b2[o] : 0.f;
        #pragma unroll
        for (int poly = 0; poly < POLYS; ++poly)
            #pragma unroll
            for (int p = 0; p < NUM_PTS; ++p)
                acc[poly][p] = valid ? bias : 0.f;
    }
    if (valid) {
        const float* wrow = w2 + (size_t)o * (C_MID * 3);
        for (int c = 0; c < C_MID; ++c) {
            float w0 = wrow[c * 3 + 0];
            float w1v = wrow[c * 3 + 1];
            float w2v = wrow[c * 3 + 2];
            #pragma unroll
            for (int poly = 0; poly < POLYS; ++poly) {
                const float* ys = &s_y1[poly][c][0];
                float4 a = *(const float4*)ys;        // [pad, p0, p1, p2]
                float4 b = *(const float4*)(ys + 4);  // [p3, p4, pad, pad]
                acc[poly][0] += w0 * a.x + w1v * a.y + w2v * a.z;
                acc[poly][1] += w0 * a.y + w1v * a.z + w2v * a.w;
                acc[poly][2] += w0 * a.z + w1v * a.w + w2v * b.x;
                acc[poly][3] += w0 * a.w + w1v * b.x + w2v * b.y;
                acc[poly][4] += w0 * b.x + w1v * b.y + w2v * b.z;
            }
        }
    }
    // ReLU
    #pragma unroll
    for (int poly = 0; poly < POLYS; ++poly)
        #pragma unroll
        for (int p = 0; p < NUM_PTS; ++p)
            acc[poly][p] = fmaxf(acc[poly][p], 0.f);

    // ---- LayerNorm over 224 channels: wave shuffle reduce + cross-wave LDS ----
    const int wave = t >> 6;
    const int lane = t & 63;
    #pragma unroll
    for (int poly = 0; poly < POLYS; ++poly) {
        #pragma unroll
        for (int p = 0; p < NUM_PTS; ++p) {
            float s = acc[poly][p];
            float q = s * s;
            #pragma unroll
            for (int m = 32; m >= 1; m >>= 1) {
                s += __shfl_xor(s, m, 64);
                q += __shfl_xor(q, m, 64);
            }
            if (lane == 0) {
                s_red[wave][poly][p][0] = s;
                s_red[wave][poly][p][1] = q;
            }
        }
    }
    __syncthreads();
    if (t < POLYS * NUM_PTS) {
        int poly = t / NUM_PTS, p = t % NUM_PTS;
        float s = 0.f, q = 0.f;
        #pragma unroll
        for (int w = 0; w < 4; ++w) {
            s += s_red[w][poly][p][0];
            q += s_red[w][poly][p][1];
        }
        float mu  = s * (1.f / C_OUT);
        float var = fmaxf(q * (1.f / C_OUT) - mu * mu, 0.f);
        s_stats[poly][p][0] = mu;
        s_stats[poly][p][1] = rsqrtf(var + 1e-5f);
    }
    __syncthreads();
    if (valid) {
        float g = gamma[o], bt = beta[o];
        #pragma unroll
        for (int poly = 0; poly < POLYS; ++poly) {
            size_t kk = (size_t)(k0 + poly);
            #pragma unroll
            for (int p = 0; p < NUM_PTS; ++p) {
                float mu = s_stats[poly][p][0], rstd = s_stats[poly][p][1];
                float v = (acc[poly][p] - mu) * rstd * g + bt;
                out[(kk * NUM_PTS + p) * GEO_DIM + PE_DIM + o] = v;
            }
        }
    }
}

extern "C" void kernel_launch(void* const* d_in, const int* in_sizes, int n_in,
                              void* d_out, int out_size, void* d_ws, size_t ws_size,
                              hipStream_t stream) {
    const float* geoms   = (const float*)d_in[0];
    const int*   lengths = (const int*)d_in[1];
    const float* w1      = (const float*)d_in[2];
    const float* b1      = (const float*)d_in[3];
    const float* w2      = (const float*)d_in[4];
    const float* b2      = (const float*)d_in[5];
    const float* gamma   = (const float*)d_in[6];
    const float* beta    = (const float*)d_in[7];
    const int*   roi_w   = (const int*)d_in[8];
    const int*   roi_h   = (const int*)d_in[9];
    float* out = (float*)d_out;

    dim3 grid(K_POLY / POLYS), block(THREADS);
    hipLaunchKernelGGL(geo_encoder, grid, block, 0, stream,
                       geoms, lengths, w1, b1, w2, b2, gamma, beta, roi_w, roi_h, out);
}

// Round 2
// 248.933 us; speedup vs baseline: 2.0599x; 2.0599x over previous
//
#include <hip/hip_runtime.h>
#include <math.h>

#define K_POLY   20000
#define PMAX     30
#define NUM_PTS  5
#define C_MID    112
#define C_OUT    224
#define PE_DIM   32
#define GEO_DIM  256
#define PB       16              // polys per block
#define THREADS  256
#define MPAD     96              // 3 M-tiles of 32 (80 real rows)
#define YPOLY    20              // s_y1 poly slots (covers M-pad rows)
#define YSTRIDE  136             // c-stride in bf16 elems (112 used, pad for banks)
// Wp packed layout: [dk(3)][ntile(8)][kstep(7)][khalf(2)][n(32)][j(8)] bf16
#define WP_ELEMS (3*8*7*2*32*8)  // 86016 elems = 172032 bytes

typedef __attribute__((ext_vector_type(8)))  short short8;
typedef __attribute__((ext_vector_type(16))) float f32x16;

__device__ inline unsigned short f2bf(float f) {
    union { float f; unsigned u; } v; v.f = f;
    return (unsigned short)((v.u + 0x7fffu + ((v.u >> 16) & 1u)) >> 16);
}

// ---- prepack w2 fp32 [224][112][3] -> bf16 B-fragment order in d_ws ----
__global__ void pack_w2(const float* __restrict__ w2, unsigned short* __restrict__ Wp) {
    int i = blockIdx.x * 256 + threadIdx.x;
    if (i >= WP_ELEMS) return;
    int j  = i & 7;
    int n  = (i >> 3) & 31;
    int kh = (i >> 8) & 1;
    int t  = i >> 9;             // (dk*8+nt)*7 + ks
    int ks = t % 7;
    int rest = t / 7;
    int nt = rest & 7;
    int dk = rest >> 3;
    int c = ks * 16 + kh * 8 + j;
    int o = nt * 32 + n;
    float v = (o < C_OUT && c < C_MID) ? w2[(o * C_MID + c) * 3 + dk] : 0.f;
    Wp[i] = f2bf(v);
}

__global__ __launch_bounds__(THREADS) void geo_encoder(
    const float* __restrict__ geoms, const int* __restrict__ lengths,
    const float* __restrict__ w1, const float* __restrict__ b1,
    const float* __restrict__ b2,
    const float* __restrict__ gamma, const float* __restrict__ beta,
    const int* __restrict__ roi_w, const int* __restrict__ roi_h,
    const unsigned short* __restrict__ Wp,
    float* __restrict__ out)
{
    __shared__ __align__(16) unsigned short s_y1[YPOLY][7][YSTRIDE]; // bf16 conv1 out, halo pos 0..6
    __shared__ float s_geo[PB][PMAX][2];
    __shared__ float s_cum[PB][PMAX];
    __shared__ float s_seg[PB][PMAX - 1];
    __shared__ float s_pts[PB][NUM_PTS][2];
    __shared__ float s_part[32][5][2];   // per-(row-in-mtile, wave) partial sum/sumsq
    __shared__ float s_stats[32][2];     // mu, rstd per row-in-mtile
    __shared__ int   s_len[PB];

    const int t  = threadIdx.x;
    const int k0 = blockIdx.x * PB;

    // ---- zero s_y1 (halo rows, pad polys, everything) ----
    {
        unsigned int* z = (unsigned int*)&s_y1[0][0][0];
        for (int i = t; i < (YPOLY * 7 * YSTRIDE) / 2; i += THREADS) z[i] = 0u;
    }
    // ---- stage geoms + lengths ----
    {
        const float* src = geoms + (size_t)k0 * (PMAX * 2);
        float* dst = &s_geo[0][0][0];
        for (int i = t; i < PB * PMAX * 2; i += THREADS) dst[i] = src[i];
        if (t < PB) s_len[t] = lengths[k0 + t];
    }
    __syncthreads();

    // ---- per-poly seg/cum (bitwise cumsum order) ----
    if (t < PB) {
        int L = s_len[t];
        float cum = 0.f;
        s_cum[t][0] = 0.f;
        for (int i = 0; i < PMAX - 1; ++i) {
            float seg = 0.f;
            if (i < L - 1) {
                float dx = s_geo[t][i + 1][0] - s_geo[t][i][0];
                float dy = s_geo[t][i + 1][1] - s_geo[t][i][1];
                float sq = dx * dx + dy * dy;
                seg = (sq > 0.f) ? sqrtf(sq) : 0.f;
            }
            s_seg[t][i] = seg;
            cum += seg;
            s_cum[t][i + 1] = cum;
        }
    }
    __syncthreads();

    // ---- resample: one point per thread ----
    const float roiw  = (float)roi_w[0], roih = (float)roi_h[0];
    const float halfx = roiw * 0.5f, halfy = roih * 0.5f;
    if (t < PB * NUM_PTS) {
        int poly = t / NUM_PTS, j = t % NUM_PTS;
        int L = s_len[poly];
        float total = s_cum[poly][PMAX - 1];
        float px, py;
        if (total < 1e-6f) {
            px = s_geo[poly][0][0];
            py = s_geo[poly][0][1];
        } else {
            float target = total * (0.25f * (float)j);
            int idx = PMAX;
            for (int i = 0; i < PMAX; ++i) {
                if (s_cum[poly][i] >= target) { idx = i; break; }
            }
            idx = max(1, min(idx, L - 1));
            float tt = (target - s_cum[poly][idx - 1]) / (s_seg[poly][idx - 1] + 1e-8f);
            float x0 = s_geo[poly][idx - 1][0], y0 = s_geo[poly][idx - 1][1];
            px = x0 + tt * (s_geo[poly][idx][0] - x0);
            py = y0 + tt * (s_geo[poly][idx][1] - y0);
        }
        float cx = (px + halfx) / roiw;
        float cy = (py + halfy) / roih;
        s_pts[poly][j][0] = cx;
        s_pts[poly][j][1] = cy;
        float* co = out + (size_t)K_POLY * NUM_PTS * GEO_DIM + ((size_t)(k0 + poly) * NUM_PTS + j) * 2;
        co[0] = cx;
        co[1] = cy;
    }
    __syncthreads();

    // ---- PE: channels 0..31 straight to global ----
    for (int i = t; i < PB * NUM_PTS * PE_DIM; i += THREADS) {
        int poly = i / (NUM_PTS * PE_DIM);
        int r = i % (NUM_PTS * PE_DIM);
        int p = r / PE_DIM;
        int f = r % PE_DIM;
        int d = f >> 4;
        int inner = f & 15;
        int fr = inner & 7;
        int isc = inner >> 3;
        float x = s_pts[poly][p][d];
        float arg = x * ((float)(1 << fr) * 3.14159265358979323846f);
        float v = isc ? cosf(arg) : sinf(arg);
        out[((size_t)(k0 + poly) * NUM_PTS + p) * GEO_DIM + f] = v;
    }

    // ---- conv1 (2->112) + ReLU -> bf16 LDS tile [poly][pos+1][c] ----
    for (int i = t; i < PB * NUM_PTS * C_MID; i += THREADS) {
        int poly = i / (NUM_PTS * C_MID);
        int r = i % (NUM_PTS * C_MID);
        int p = r / C_MID;
        int c = r % C_MID;
        float acc = b1[c];
        const float* w = w1 + c * 6;
        #pragma unroll
        for (int ch = 0; ch < 2; ++ch) {
            #pragma unroll
            for (int dk = 0; dk < 3; ++dk) {
                int pp = p + dk - 1;
                float xv = (pp >= 0 && pp < NUM_PTS) ? s_pts[poly][pp][ch] : 0.f;
                acc += xv * w[ch * 3 + dk];
            }
        }
        s_y1[poly][p + 1][c] = f2bf(fmaxf(acc, 0.f));
    }
    __syncthreads();

    // ---- conv2 via MFMA: 3 shifted GEMMs over K=112, N padded to 256 ----
    const int lane = t & 63;
    const int wave = t >> 6;
    const int n    = lane & 31;
    const int kh   = lane >> 5;
    const int nt0  = wave * 2;
    const int nt1  = wave * 2 + 1;
    const bool has1 = (nt1 < 7);

    float bias0 = b2[nt0 * 32 + n];
    float g0    = gamma[nt0 * 32 + n];
    float be0   = beta[nt0 * 32 + n];
    float bias1 = has1 ? b2[nt1 * 32 + n] : 0.f;
    float g1    = has1 ? gamma[nt1 * 32 + n] : 0.f;
    float be1   = has1 ? beta[nt1 * 32 + n] : 0.f;

    const unsigned short* wp0 = Wp + nt0 * (7 * 512) + lane * 8;
    const unsigned short* wp1 = Wp + nt1 * (7 * 512) + lane * 8;
    const unsigned short* y1base = &s_y1[0][0][0];

    for (int mt = 0; mt < 3; ++mt) {
        // A-row for this lane
        int rA = mt * 32 + (lane & 31);
        int polyA = rA / 5;
        int pA = rA - polyA * 5;
        const unsigned short* ap = y1base + (polyA * 7 + pA) * YSTRIDE + kh * 8;

        f32x16 acc0, acc1;
        #pragma unroll
        for (int i = 0; i < 16; ++i) { acc0[i] = 0.f; acc1[i] = 0.f; }

        #pragma unroll
        for (int dk = 0; dk < 3; ++dk) {
            #pragma unroll
            for (int ks = 0; ks < 7; ++ks) {
                short8 a  = *(const short8*)(ap + dk * YSTRIDE + ks * 16);
                short8 b0 = *(const short8*)(wp0 + dk * 28672 + ks * 512);
                acc0 = __builtin_amdgcn_mfma_f32_32x32x16_bf16(a, b0, acc0, 0, 0, 0);
                if (has1) {
                    short8 b1v = *(const short8*)(wp1 + dk * 28672 + ks * 512);
                    acc1 = __builtin_amdgcn_mfma_f32_32x32x16_bf16(a, b1v, acc1, 0, 0, 0);
                }
            }
        }

        // bias + ReLU
        float y0[16], y1v[16];
        #pragma unroll
        for (int i = 0; i < 16; ++i) {
            y0[i]  = fmaxf(acc0[i] + bias0, 0.f);
            y1v[i] = has1 ? fmaxf(acc1[i] + bias1, 0.f) : 0.f;
        }

        // per-wave partial LN stats over this wave's 64 channels
        #pragma unroll
        for (int i = 0; i < 16; ++i) {
            float s = y0[i] + y1v[i];
            float q = y0[i] * y0[i] + y1v[i] * y1v[i];
            #pragma unroll
            for (int m = 16; m >= 1; m >>= 1) {
                s += __shfl_xor(s, m, 64);
                q += __shfl_xor(q, m, 64);
            }
            if (n == 0) {
                int mrow = (i & 3) + 8 * (i >> 2) + 4 * kh;
                s_part[mrow][wave][0] = s;
                s_part[mrow][wave][1] = q;
            }
        }
        __syncthreads();

        if (t < 32) {
            float s = 0.f, q = 0.f;
            #pragma unroll
            for (int w = 0; w < 4; ++w) {
                s += s_part[t][w][0];
                q += s_part[t][w][1];
            }
            float mu  = s * (1.f / C_OUT);
            float var = fmaxf(q * (1.f / C_OUT) - mu * mu, 0.f);
            s_stats[t][0] = mu;
            s_stats[t][1] = rsqrtf(var + 1e-5f);
        }
        __syncthreads();

        // normalize + store (channels 32..255 of out)
        #pragma unroll
        for (int i = 0; i < 16; ++i) {
            int mrow = (i & 3) + 8 * (i >> 2) + 4 * kh;
            int rr = mt * 32 + mrow;
            if (rr < PB * NUM_PTS) {
                float mu = s_stats[mrow][0], rs = s_stats[mrow][1];
                int poly = rr / 5;
                int p = rr - poly * 5;
                size_t base = ((size_t)(k0 + poly) * NUM_PTS + p) * GEO_DIM + PE_DIM;
                out[base + nt0 * 32 + n] = (y0[i] - mu) * rs * g0 + be0;
                if (has1)
                    out[base + nt1 * 32 + n] = (y1v[i] - mu) * rs * g1 + be1;
            }
        }
    }
}

extern "C" void kernel_launch(void* const* d_in, const int* in_sizes, int n_in,
                              void* d_out, int out_size, void* d_ws, size_t ws_size,
                              hipStream_t stream) {
    const float* geoms   = (const float*)d_in[0];
    const int*   lengths = (const int*)d_in[1];
    const float* w1      = (const float*)d_in[2];
    const float* b1      = (const float*)d_in[3];
    const float* w2      = (const float*)d_in[4];
    const float* b2      = (const float*)d_in[5];
    const float* gamma   = (const float*)d_in[6];
    const float* beta    = (const float*)d_in[7];
    const int*   roi_w   = (const int*)d_in[8];
    const int*   roi_h   = (const int*)d_in[9];
    float* out = (float*)d_out;
    unsigned short* Wp = (unsigned short*)d_ws;  // 172032 bytes

    hipLaunchKernelGGL(pack_w2, dim3((WP_ELEMS + 255) / 256), dim3(256), 0, stream, w2, Wp);
    hipLaunchKernelGGL(geo_encoder, dim3(K_POLY / PB), dim3(THREADS), 0, stream,
                       geoms, lengths, w1, b1, b2, gamma, beta, roi_w, roi_h, Wp, out);
}

// Round 3
// 216.380 us; speedup vs baseline: 2.3697x; 1.1504x over previous
//
#include <hip/hip_runtime.h>
#include <math.h>

#define K_POLY   20000
#define PMAX     30
#define NUM_PTS  5
#define C_MID    112
#define C_OUT    224
#define PE_DIM   32
#define GEO_DIM  256

#define POLYS_A  32                      // polys per prep block
#define WP_ELEMS (21*7*64*8)             // 75264 bf16 = 150528 B, no padding
#define Y1_ROW   (7*C_MID)               // 784 bf16 per poly (halo layout)
#define M_ROWS   (K_POLY*NUM_PTS)        // 100000
#define N_WAVES  (M_ROWS/32)             // 3125

typedef __attribute__((ext_vector_type(8)))  short short8;
typedef __attribute__((ext_vector_type(16))) float f32x16;

__device__ inline unsigned short f2bf(float f) {
    union { float f; unsigned u; } v; v.f = f;
    return (unsigned short)((v.u + 0x7fffu + ((v.u >> 16) & 1u)) >> 16);
}

// ============ Kernel A: pack w2 + resample + PE + conv1 -> y1 (global bf16) ============
__global__ __launch_bounds__(256) void prep_kernel(
    const float* __restrict__ geoms, const int* __restrict__ lengths,
    const float* __restrict__ w1, const float* __restrict__ b1,
    const float* __restrict__ w2,
    const int* __restrict__ roi_w, const int* __restrict__ roi_h,
    unsigned short* __restrict__ Wp, unsigned short* __restrict__ y1g,
    float* __restrict__ out)
{
    __shared__ float s_geo[POLYS_A][PMAX][2];
    __shared__ float s_cum[POLYS_A][PMAX];
    __shared__ float s_seg[POLYS_A][PMAX - 1];
    __shared__ float s_pts[POLYS_A][NUM_PTS][2];
    __shared__ float s_w1[C_MID * 6];
    __shared__ float s_b1[C_MID];
    __shared__ int   s_len[POLYS_A];

    const int t  = threadIdx.x;
    const int k0 = blockIdx.x * POLYS_A;

    // ---- pack w2 into B-fragment order: Wp[((ks*7+nt)*64 + lane)*8 + j] ----
    {
        int gtid = blockIdx.x * 256 + t;
        if (gtid < WP_ELEMS) {
            int j    = gtid & 7;
            int lane = (gtid >> 3) & 63;
            int grp  = gtid >> 9;          // ks*7 + nt
            int nt   = grp % 7;
            int ks   = grp / 7;
            int kh   = lane >> 5, n = lane & 31;
            int k    = ks * 16 + kh * 8 + j;   // 0..335, k = dk*112 + c
            int dk   = k / C_MID;
            int c    = k - dk * C_MID;
            int o    = nt * 32 + n;
            Wp[gtid] = f2bf(w2[(o * C_MID + c) * 3 + dk]);
        }
    }

    // ---- stage ----
    {
        const float* src = geoms + (size_t)k0 * (PMAX * 2);
        float* dst = &s_geo[0][0][0];
        for (int i = t; i < POLYS_A * PMAX * 2; i += 256) dst[i] = src[i];
        if (t < POLYS_A) s_len[t] = lengths[k0 + t];
        for (int i = t; i < C_MID * 6; i += 256) s_w1[i] = w1[i];
        if (t < C_MID) s_b1[t] = b1[t];
    }
    __syncthreads();

    // ---- per-poly cum/seg (bitwise cumsum order) ----
    if (t < POLYS_A) {
        int L = s_len[t];
        float cum = 0.f;
        s_cum[t][0] = 0.f;
        for (int i = 0; i < PMAX - 1; ++i) {
            float seg = 0.f;
            if (i < L - 1) {
                float dx = s_geo[t][i + 1][0] - s_geo[t][i][0];
                float dy = s_geo[t][i + 1][1] - s_geo[t][i][1];
                float sq = dx * dx + dy * dy;
                seg = (sq > 0.f) ? sqrtf(sq) : 0.f;
            }
            s_seg[t][i] = seg;
            cum += seg;
            s_cum[t][i + 1] = cum;
        }
    }
    __syncthreads();

    // ---- resample ----
    const float roiw  = (float)roi_w[0], roih = (float)roi_h[0];
    const float halfx = roiw * 0.5f, halfy = roih * 0.5f;
    if (t < POLYS_A * NUM_PTS) {
        int poly = t / NUM_PTS, j = t % NUM_PTS;
        int L = s_len[poly];
        float total = s_cum[poly][PMAX - 1];
        float px, py;
        if (total < 1e-6f) {
            px = s_geo[poly][0][0];
            py = s_geo[poly][0][1];
        } else {
            float target = total * (0.25f * (float)j);
            int idx = PMAX;
            for (int i = 0; i < PMAX; ++i) {
                if (s_cum[poly][i] >= target) { idx = i; break; }
            }
            idx = max(1, min(idx, L - 1));
            float tt = (target - s_cum[poly][idx - 1]) / (s_seg[poly][idx - 1] + 1e-8f);
            float x0 = s_geo[poly][idx - 1][0], y0 = s_geo[poly][idx - 1][1];
            px = x0 + tt * (s_geo[poly][idx][0] - x0);
            py = y0 + tt * (s_geo[poly][idx][1] - y0);
        }
        float cx = (px + halfx) / roiw;
        float cy = (py + halfy) / roih;
        s_pts[poly][j][0] = cx;
        s_pts[poly][j][1] = cy;
        float* co = out + (size_t)K_POLY * NUM_PTS * GEO_DIM + ((size_t)(k0 + poly) * NUM_PTS + j) * 2;
        co[0] = cx;
        co[1] = cy;
    }
    __syncthreads();

    // ---- PE: channels 0..31 ----
    for (int i = t; i < POLYS_A * NUM_PTS * PE_DIM; i += 256) {
        int poly = i / (NUM_PTS * PE_DIM);
        int r = i % (NUM_PTS * PE_DIM);
        int p = r / PE_DIM;
        int f = r % PE_DIM;
        int d = f >> 4;
        int inner = f & 15;
        int fr = inner & 7;
        int isc = inner >> 3;
        float x = s_pts[poly][p][d];
        float arg = x * ((float)(1 << fr) * 3.14159265358979323846f);
        float v = isc ? __cosf(arg) : __sinf(arg);
        out[((size_t)(k0 + poly) * NUM_PTS + p) * GEO_DIM + f] = v;
    }

    // ---- conv1 + ReLU -> y1 global bf16, halo layout [poly][7][112] ----
    for (int i = t; i < POLYS_A * Y1_ROW; i += 256) {
        int poly = i / Y1_ROW;
        int r = i % Y1_ROW;
        int slot = r / C_MID;
        int c = r - slot * C_MID;
        unsigned short v = 0;
        if (slot >= 1 && slot <= 5) {
            int p = slot - 1;
            float acc = s_b1[c];
            const float* w = &s_w1[c * 6];
            #pragma unroll
            for (int ch = 0; ch < 2; ++ch) {
                #pragma unroll
                for (int dk = 0; dk < 3; ++dk) {
                    int pp = p + dk - 1;
                    float xv = (pp >= 0 && pp < NUM_PTS) ? s_pts[poly][pp][ch] : 0.f;
                    acc += xv * w[ch * 3 + dk];
                }
            }
            v = f2bf(fmaxf(acc, 0.f));
        }
        y1g[(size_t)(k0 + poly) * Y1_ROW + r] = v;
    }
}

// ============ Kernel B: barrier-free GEMM (conv2) + ReLU + LayerNorm ============
__global__ __launch_bounds__(256, 3) void gemm_kernel(
    const unsigned short* __restrict__ y1g, const unsigned short* __restrict__ Wp,
    const float* __restrict__ b2, const float* __restrict__ gamma,
    const float* __restrict__ beta, float* __restrict__ out)
{
    const int wave = threadIdx.x >> 6;
    const int lane = threadIdx.x & 63;
    const int wid  = blockIdx.x * 4 + wave;
    if (wid >= N_WAVES) return;
    const int r0 = wid * 32;
    const int n  = lane & 31;
    const int kh = lane >> 5;

    // A-operand: this lane covers row r0 + (lane&31), k-half kh
    const int arow = r0 + n;
    const int poly = arow / NUM_PTS;
    const int p    = arow - poly * NUM_PTS;
    const unsigned short* ap = y1g + ((size_t)poly * 7 + p) * C_MID + kh * 8;
    const unsigned short* wl = Wp + lane * 8;

    f32x16 acc[7];
    #pragma unroll
    for (int nt = 0; nt < 7; ++nt)
        #pragma unroll
        for (int i = 0; i < 16; ++i) acc[nt][i] = 0.f;

    #pragma unroll 1
    for (int ks = 0; ks < 21; ++ks) {
        short8 a = *(const short8*)(ap + ks * 16);
        #pragma unroll
        for (int nt = 0; nt < 7; ++nt) {
            short8 b = *(const short8*)(wl + ((ks * 7 + nt) << 9));
            acc[nt] = __builtin_amdgcn_mfma_f32_32x32x16_bf16(a, b, acc[nt], 0, 0, 0);
        }
    }

    // bias + ReLU in place
    float g[7], be[7];
    #pragma unroll
    for (int nt = 0; nt < 7; ++nt) {
        int col = nt * 32 + n;
        float bias = b2[col];
        g[nt]  = gamma[col];
        be[nt] = beta[col];
        #pragma unroll
        for (int i = 0; i < 16; ++i)
            acc[nt][i] = fmaxf(acc[nt][i] + bias, 0.f);
    }

    // LayerNorm: each row lives in one 32-lane half at reg i; butterfly within half
    #pragma unroll
    for (int i = 0; i < 16; ++i) {
        float s = 0.f, q = 0.f;
        #pragma unroll
        for (int nt = 0; nt < 7; ++nt) {
            float v = acc[nt][i];
            s += v;
            q += v * v;
        }
        #pragma unroll
        for (int m = 16; m >= 1; m >>= 1) {
            s += __shfl_xor(s, m, 64);
            q += __shfl_xor(q, m, 64);
        }
        float mu  = s * (1.f / C_OUT);
        float var = fmaxf(q * (1.f / C_OUT) - mu * mu, 0.f);
        float rs  = rsqrtf(var + 1e-5f);

        int rg = r0 + (i & 3) + 8 * (i >> 2) + 4 * kh;
        size_t base = (size_t)rg * GEO_DIM + PE_DIM + n;
        #pragma unroll
        for (int nt = 0; nt < 7; ++nt)
            out[base + nt * 32] = (acc[nt][i] - mu) * rs * g[nt] + be[nt];
    }
}

extern "C" void kernel_launch(void* const* d_in, const int* in_sizes, int n_in,
                              void* d_out, int out_size, void* d_ws, size_t ws_size,
                              hipStream_t stream) {
    const float* geoms   = (const float*)d_in[0];
    const int*   lengths = (const int*)d_in[1];
    const float* w1      = (const float*)d_in[2];
    const float* b1      = (const float*)d_in[3];
    const float* w2      = (const float*)d_in[4];
    const float* b2      = (const float*)d_in[5];
    const float* gamma   = (const float*)d_in[6];
    const float* beta    = (const float*)d_in[7];
    const int*   roi_w   = (const int*)d_in[8];
    const int*   roi_h   = (const int*)d_in[9];
    float* out = (float*)d_out;

    unsigned short* Wp  = (unsigned short*)d_ws;            // 150528 B
    unsigned short* y1g = (unsigned short*)d_ws + WP_ELEMS; // 20000*784*2 B, 512B-aligned

    hipLaunchKernelGGL(prep_kernel, dim3(K_POLY / POLYS_A), dim3(256), 0, stream,
                       geoms, lengths, w1, b1, w2, roi_w, roi_h, Wp, y1g, out);
    hipLaunchKernelGGL(gemm_kernel, dim3((N_WAVES + 3) / 4), dim3(256), 0, stream,
                       y1g, Wp, b2, gamma, beta, out);
}